// Round 3
// baseline (782.164 us; speedup 1.0000x reference)
//
#include <hip/hip_runtime.h>
#include <hip/hip_bf16.h>
#include <stdint.h>

// GraphTripleConv: B=32, O=4096, T=16384, D=H=DOUT=128
// out = [new_obj (B*O*128) | new_p (B*T*128)], f32
#define Bn 32
#define On 4096
#define Tn 16384
#define Dn 128

typedef short short8 __attribute__((ext_vector_type(8)));
typedef float f32x4 __attribute__((ext_vector_type(4)));

__device__ inline short f2bf(float f) {
  union { float f; uint32_t u; } v; v.f = f;
  uint32_t u = v.u;
  uint32_t r = u + 0x7fffu + ((u >> 16) & 1u);  // RNE
  return (short)(r >> 16);
}
__device__ inline float bf2f(unsigned short u) {
  union { uint32_t ui; float f; } cv; cv.ui = ((uint32_t)u) << 16; return cv.f;
}

// ---- weight prep: f32 [K][N] -> bf16 [N][K] (transposed so MFMA B-frag = 16B load)
__global__ void prep_weights(const float* __restrict__ W1, const float* __restrict__ W2,
                             const float* __restrict__ W3, const float* __restrict__ W4,
                             short* __restrict__ w1t, short* __restrict__ w2t,
                             short* __restrict__ w3t, short* __restrict__ w4t) {
  int i = blockIdx.x * 256 + threadIdx.x;
  if (i < 49152) {
    int n = i / 384, k = i % 384;
    w1t[i] = f2bf(W1[k * 128 + n]);
  } else if (i < 49152 + 32768) {
    int j = i - 49152;
    int n = j / 128, k = j % 128;
    w2t[j] = f2bf(W2[k * 384 + 128 + n]);   // only cols 128..383 live (new_s dead)
  } else if (i < 49152 + 32768 + 16384) {
    int j = i - 81920;
    int n = j / 128, k = j % 128;
    w3t[j] = f2bf(W3[k * 128 + n]);
  } else if (i < 114688) {
    int j = i - 98304;
    int n = j / 128, k = j % 128;
    w4t[j] = f2bf(W4[k * 128 + n]);
  }
}

// ---- counting-sort index build: hist -> per-batch exclusive scan -> scatter ids
__global__ void hist_kernel(const int* __restrict__ edges, int* __restrict__ hist) {
  int tid = blockIdx.x * 256 + threadIdx.x;   // 0..B*T-1
  int b = tid >> 14;
  int o = edges[tid * 2 + 1];
  atomicAdd(&hist[b * On + o], 1);
}

__global__ void scan_kernel(const int* __restrict__ hist, int* __restrict__ offs) {
  __shared__ int sdata[1024];
  int b = blockIdx.x;
  int i = threadIdx.x;
  int base = b * On;
  int h[4]; int s = 0;
#pragma unroll
  for (int j = 0; j < 4; j++) { h[j] = hist[base + i * 4 + j]; s += h[j]; }
  sdata[i] = s;
  int tsum = s;
  for (int off = 1; off < 1024; off <<= 1) {
    __syncthreads();
    int t = (i >= off) ? sdata[i - off] : 0;
    __syncthreads();
    sdata[i] += t;
  }
  __syncthreads();
  int excl = sdata[i] - tsum + b * Tn;   // global edge position base
#pragma unroll
  for (int j = 0; j < 4; j++) { offs[base + i * 4 + j] = excl; excl += h[j]; }
}

__global__ void scatter_kernel(const int* __restrict__ edges, const int* __restrict__ offs,
                               int* __restrict__ fill, unsigned short* __restrict__ eidx) {
  int tid = blockIdx.x * 256 + threadIdx.x;
  int b = tid >> 14, t = tid & 16383;
  int o = edges[tid * 2 + 1];
  int pos = offs[b * On + o] + atomicAdd(&fill[b * On + o], 1);
  eidx[pos] = (unsigned short)t;
}

// ---- edge MLP: gather [s|p|o] (384) -> GEMM1(K=384,N=128) -> GEMM2(K=128,N=256)
// cols 0..127 -> new_p (store); cols 128..255 -> new_o:
//   o_scr != nullptr : plain bf16 stores to scratch (sort path)
//   else             : f32 atomicAdd into pooled (fallback path)
__global__ __launch_bounds__(256, 4) void edge_mlp(
    const float* __restrict__ obj, const float* __restrict__ pred,
    const int* __restrict__ edges,
    const short* __restrict__ w1t, const short* __restrict__ w2t,
    const float* __restrict__ b1, const float* __restrict__ g1, const float* __restrict__ be1,
    const float* __restrict__ b2, const float* __restrict__ g2, const float* __restrict__ be2,
    float* __restrict__ out_p, float* __restrict__ pooled, float* __restrict__ counts,
    short* __restrict__ o_scr)
{
  __shared__ short xs[32 * 384];   // 24 KB; reused as h1 (32x128 bf16) after GEMM1
  __shared__ int olds[32];
  char* base = (char*)xs;

  const float invs = 1.0f / sqrtf(1.001f);   // 1/sqrt(1+EPS)
  int blk = blockIdx.x;
  int b = blk >> 9;                 // 512 blocks per batch (16384/32)
  int t0 = (blk & 511) << 5;
  int tid = threadIdx.x;

  // ---- stage gathered input rows as bf16 into LDS (8 threads per row, 48 elems each)
  {
    int r = tid >> 3, seg = tid & 7;
    int t = t0 + r;
    int e = (b * Tn + t) * 2;
    int sidx = edges[e], oidx = edges[e + 1];
    if (seg == 0) { olds[r] = oidx; if (counts) atomicAdd(&counts[b * On + oidx], 1.0f); }
    const float* srow = obj + (size_t)(b * On + sidx) * Dn;
    const float* prow = pred + (size_t)(b * Tn + t) * Dn;
    const float* orow = obj + (size_t)(b * On + oidx) * Dn;
#pragma unroll
    for (int i = 0; i < 6; i++) {
      int k = seg * 48 + i * 8;     // 8-groups never straddle the 128-boundaries
      const float* src = (k < 128) ? (srow + k) : (k < 256 ? prow + (k - 128) : orow + (k - 256));
      float4 v0 = *(const float4*)(src);
      float4 v1 = *(const float4*)(src + 4);
      short8 pk;
      pk[0]=f2bf(v0.x); pk[1]=f2bf(v0.y); pk[2]=f2bf(v0.z); pk[3]=f2bf(v0.w);
      pk[4]=f2bf(v1.x); pk[5]=f2bf(v1.y); pk[6]=f2bf(v1.z); pk[7]=f2bf(v1.w);
      *(short8*)(base + r * 768 + ((k * 2) ^ ((r & 7) << 4))) = pk;
    }
  }
  __syncthreads();

  int wave = tid >> 6, lane = tid & 63;
  int l15 = lane & 15, l4 = lane >> 4;

  // ---- GEMM1: 32x384 @ 384x128 ; wave owns 32 output cols
  f32x4 acc1[2][2] = {};
  int n0 = wave * 32;
  for (int kk = 0; kk < 12; kk++) {
    short8 a[2], bb[2];
#pragma unroll
    for (int m = 0; m < 2; m++) {
      int row = m * 16 + l15;
      a[m] = *(short8*)(base + row * 768 + ((kk * 64 + 16 * l4) ^ ((row & 7) << 4)));
    }
#pragma unroll
    for (int n = 0; n < 2; n++) bb[n] = *(const short8*)&w1t[(n0 + n * 16 + l15) * 384 + kk * 32 + 8 * l4];
#pragma unroll
    for (int m = 0; m < 2; m++)
#pragma unroll
      for (int n = 0; n < 2; n++)
        acc1[m][n] = __builtin_amdgcn_mfma_f32_16x16x32_bf16(a[m], bb[n], acc1[m][n], 0, 0, 0);
  }
  __syncthreads();   // all waves done reading xs before h1 overwrites it

  // epilogue: affine + relu -> bf16 h1 in LDS (reusing xs region)
#pragma unroll
  for (int n = 0; n < 2; n++) {
    int col = n0 + n * 16 + l15;
    float gs = g1[col] * invs;
    float add = b1[col] * gs + be1[col];
#pragma unroll
    for (int m = 0; m < 2; m++)
#pragma unroll
      for (int rr = 0; rr < 4; rr++) {
        int row = m * 16 + l4 * 4 + rr;
        float v = fmaxf(acc1[m][n][rr] * gs + add, 0.0f);
        *(short*)(base + row * 256 + ((col * 2) ^ ((row & 7) << 4))) = f2bf(v);
      }
  }
  __syncthreads();

  // ---- GEMM2: 32x128 @ 128x256 (live cols only); wave owns 64 output cols
  f32x4 acc2[2][4] = {};
  int n0b = wave * 64;
  for (int kk = 0; kk < 4; kk++) {
    short8 a[2], bb[4];
#pragma unroll
    for (int m = 0; m < 2; m++) {
      int row = m * 16 + l15;
      a[m] = *(short8*)(base + row * 256 + ((kk * 64 + 16 * l4) ^ ((row & 7) << 4)));
    }
#pragma unroll
    for (int n = 0; n < 4; n++) bb[n] = *(const short8*)&w2t[(n0b + n * 16 + l15) * 128 + kk * 32 + 8 * l4];
#pragma unroll
    for (int m = 0; m < 2; m++)
#pragma unroll
      for (int n = 0; n < 4; n++)
        acc2[m][n] = __builtin_amdgcn_mfma_f32_16x16x32_bf16(a[m], bb[n], acc2[m][n], 0, 0, 0);
  }
  // epilogue: waves 0,1 -> new_p ; waves 2,3 -> new_o (store or atomic)
#pragma unroll
  for (int n = 0; n < 4; n++) {
    int colp = n0b + n * 16 + l15;   // 0..255
    int c2 = 128 + colp;             // original W2 output column
    float gs = g2[c2] * invs;
    float add = b2[c2] * gs + be2[c2];
#pragma unroll
    for (int m = 0; m < 2; m++)
#pragma unroll
      for (int rr = 0; rr < 4; rr++) {
        int row = m * 16 + l4 * 4 + rr;
        float v = fmaxf(acc2[m][n][rr] * gs + add, 0.0f);
        if (colp < 128) {
          out_p[(size_t)(b * Tn + t0 + row) * 128 + colp] = v;
        } else if (o_scr) {
          ((unsigned short*)o_scr)[(size_t)(b * Tn + t0 + row) * 128 + (colp - 128)] =
              (unsigned short)f2bf(v);
        } else {
          atomicAdd(&pooled[(size_t)(b * On + olds[row]) * 128 + (colp - 128)], v);
        }
      }
  }
}

// ---- gather-pool: per (b,o) sum its edge segment from o_scr, divide by count
__global__ __launch_bounds__(256) void pool_gather(
    const short* __restrict__ o_scr, const int* __restrict__ hist,
    const int* __restrict__ offs, const unsigned short* __restrict__ eidx,
    float* __restrict__ pooled)
{
  int r = blockIdx.x * 2 + (threadIdx.x >> 7);   // global obj row 0..B*O-1
  int col = threadIdx.x & 127;
  int b = r >> 12;
  int cnt = hist[r], start = offs[r];
  float s = 0.f;
  for (int k = 0; k < cnt; k++) {
    int t = eidx[start + k];
    s += bf2f(((const unsigned short*)o_scr)[((size_t)(b * Tn + t)) * 128 + col]);
  }
  pooled[(size_t)r * 128 + col] = s / fmaxf((float)cnt, 1.0f);
}

// ---- object MLP: pooled(/count) -> GEMM3(128x128) -> GEMM4(128x128), in-place on d_out
__global__ __launch_bounds__(256) void obj_mlp(
    float* __restrict__ io, const float* __restrict__ counts,
    const short* __restrict__ w3t, const short* __restrict__ w4t,
    const float* __restrict__ b3, const float* __restrict__ g3, const float* __restrict__ be3,
    const float* __restrict__ b4, const float* __restrict__ g4, const float* __restrict__ be4)
{
  __shared__ short xs[64][136];
  __shared__ short hs[64][136];
  const float invs = 1.0f / sqrtf(1.001f);
  int row0 = blockIdx.x * 64;
  int tid = threadIdx.x;
  {
    int r = tid >> 2, seg = tid & 3;
    float ic = counts ? (1.0f / fmaxf(counts[row0 + r], 1.0f)) : 1.0f;
    const float* src = io + (size_t)(row0 + r) * 128 + seg * 32;
#pragma unroll
    for (int i = 0; i < 4; i++) {
      float4 v0 = *(const float4*)(src + i * 8);
      float4 v1 = *(const float4*)(src + i * 8 + 4);
      short8 pk;
      pk[0]=f2bf(v0.x*ic); pk[1]=f2bf(v0.y*ic); pk[2]=f2bf(v0.z*ic); pk[3]=f2bf(v0.w*ic);
      pk[4]=f2bf(v1.x*ic); pk[5]=f2bf(v1.y*ic); pk[6]=f2bf(v1.z*ic); pk[7]=f2bf(v1.w*ic);
      *(short8*)&xs[r][seg * 32 + i * 8] = pk;
    }
  }
  __syncthreads();

  int wave = tid >> 6, lane = tid & 63;
  int l15 = lane & 15, l4 = lane >> 4;
  int n0 = wave * 32;

  f32x4 acc[4][2] = {};
  for (int kk = 0; kk < 4; kk++) {
    int k0 = kk * 32;
    short8 a[4], bb[2];
#pragma unroll
    for (int m = 0; m < 4; m++) a[m] = *(short8*)&xs[m * 16 + l15][k0 + 8 * l4];
#pragma unroll
    for (int n = 0; n < 2; n++) bb[n] = *(const short8*)&w3t[(n0 + n * 16 + l15) * 128 + k0 + 8 * l4];
#pragma unroll
    for (int m = 0; m < 4; m++)
#pragma unroll
      for (int n = 0; n < 2; n++)
        acc[m][n] = __builtin_amdgcn_mfma_f32_16x16x32_bf16(a[m], bb[n], acc[m][n], 0, 0, 0);
  }
#pragma unroll
  for (int n = 0; n < 2; n++) {
    int col = n0 + n * 16 + l15;
    float gs = g3[col] * invs;
    float add = b3[col] * gs + be3[col];
#pragma unroll
    for (int m = 0; m < 4; m++)
#pragma unroll
      for (int rr = 0; rr < 4; rr++) {
        float v = fmaxf(acc[m][n][rr] * gs + add, 0.0f);
        hs[m * 16 + l4 * 4 + rr][col] = f2bf(v);
      }
  }
  __syncthreads();

  f32x4 acc2[4][2] = {};
  for (int kk = 0; kk < 4; kk++) {
    int k0 = kk * 32;
    short8 a[4], bb[2];
#pragma unroll
    for (int m = 0; m < 4; m++) a[m] = *(short8*)&hs[m * 16 + l15][k0 + 8 * l4];
#pragma unroll
    for (int n = 0; n < 2; n++) bb[n] = *(const short8*)&w4t[(n0 + n * 16 + l15) * 128 + k0 + 8 * l4];
#pragma unroll
    for (int m = 0; m < 4; m++)
#pragma unroll
      for (int n = 0; n < 2; n++)
        acc2[m][n] = __builtin_amdgcn_mfma_f32_16x16x32_bf16(a[m], bb[n], acc2[m][n], 0, 0, 0);
  }
#pragma unroll
  for (int n = 0; n < 2; n++) {
    int col = n0 + n * 16 + l15;
    float gs = g4[col] * invs;
    float add = b4[col] * gs + be4[col];
#pragma unroll
    for (int m = 0; m < 4; m++)
#pragma unroll
      for (int rr = 0; rr < 4; rr++) {
        int row = m * 16 + l4 * 4 + rr;
        float v = fmaxf(acc2[m][n][rr] * gs + add, 0.0f);
        io[(size_t)(row0 + row) * 128 + col] = v;
      }
  }
}

extern "C" void kernel_launch(void* const* d_in, const int* in_sizes, int n_in,
                              void* d_out, int out_size, void* d_ws, size_t ws_size,
                              hipStream_t stream) {
  const float* obj  = (const float*)d_in[0];
  const float* pred = (const float*)d_in[1];
  const int*   edges= (const int*)d_in[2];
  const float* W1 = (const float*)d_in[3];
  const float* b1 = (const float*)d_in[4];
  const float* g1 = (const float*)d_in[5];
  const float* be1= (const float*)d_in[6];
  const float* W2 = (const float*)d_in[7];
  const float* b2 = (const float*)d_in[8];
  const float* g2 = (const float*)d_in[9];
  const float* be2= (const float*)d_in[10];
  const float* W3 = (const float*)d_in[11];
  const float* b3 = (const float*)d_in[12];
  const float* g3 = (const float*)d_in[13];
  const float* be3= (const float*)d_in[14];
  const float* W4 = (const float*)d_in[15];
  const float* b4 = (const float*)d_in[16];
  const float* g4 = (const float*)d_in[17];
  const float* be4= (const float*)d_in[18];

  float* out_obj = (float*)d_out;                           // B*O*128
  float* out_p   = (float*)d_out + (size_t)Bn * On * 128;   // B*T*128

  char* ws = (char*)d_ws;
  // weights at [0, 256KB)
  short* w1t = (short*)(ws);
  short* w2t = (short*)(ws + 49152 * 2);
  short* w3t = (short*)(ws + (49152 + 32768) * 2);
  short* w4t = (short*)(ws + (49152 + 32768 + 16384) * 2);

  const size_t OFF_HIST = 262144;                 // 512 KB (int B*O)
  const size_t OFF_OFFS = OFF_HIST + 524288;
  const size_t OFF_FILL = OFF_OFFS + 524288;
  const size_t OFF_EIDX = OFF_FILL + 524288;      // u16 B*T = 1 MB
  const size_t OFF_OSCR = 4194304;                // bf16 B*T*128 = 128 MiB
  const size_t NEED = OFF_OSCR + (size_t)Bn * Tn * 128 * 2;

  prep_weights<<<448, 256, 0, stream>>>(W1, W2, W3, W4, w1t, w2t, w3t, w4t);

  if (ws_size >= NEED) {
    // ---- sort path: no pooled atomics
    int* hist = (int*)(ws + OFF_HIST);
    int* offs = (int*)(ws + OFF_OFFS);
    int* fill = (int*)(ws + OFF_FILL);
    unsigned short* eidx = (unsigned short*)(ws + OFF_EIDX);
    short* o_scr = (short*)(ws + OFF_OSCR);

    hipMemsetAsync(hist, 0, 524288, stream);
    hipMemsetAsync(fill, 0, 524288, stream);
    hist_kernel<<<(Bn * Tn) / 256, 256, 0, stream>>>(edges, hist);
    scan_kernel<<<Bn, 1024, 0, stream>>>(hist, offs);
    scatter_kernel<<<(Bn * Tn) / 256, 256, 0, stream>>>(edges, offs, fill, eidx);
    edge_mlp<<<Bn * (Tn / 32), 256, 0, stream>>>(obj, pred, edges, w1t, w2t,
        b1, g1, be1, b2, g2, be2, out_p, nullptr, nullptr, o_scr);
    pool_gather<<<(Bn * On) / 2, 256, 0, stream>>>(o_scr, hist, offs, eidx, out_obj);
    obj_mlp<<<(Bn * On) / 64, 256, 0, stream>>>(out_obj, nullptr, w3t, w4t,
        b3, g3, be3, b4, g4, be4);
  } else {
    // ---- fallback: atomic pooling into d_out (round-1 structure, spill-free)
    float* counts = (float*)(ws + OFF_HIST);
    hipMemsetAsync(counts, 0, (size_t)Bn * On * 4, stream);
    hipMemsetAsync(out_obj, 0, (size_t)Bn * On * 128 * 4, stream);
    edge_mlp<<<Bn * (Tn / 32), 256, 0, stream>>>(obj, pred, edges, w1t, w2t,
        b1, g1, be1, b2, g2, be2, out_p, out_obj, counts, nullptr);
    obj_mlp<<<(Bn * On) / 64, 256, 0, stream>>>(out_obj, counts, w3t, w4t,
        b3, g3, be3, b4, g4, be4);
  }
}

// Round 4
// 483.235 us; speedup vs baseline: 1.6186x; 1.6186x over previous
//
#include <hip/hip_runtime.h>
#include <hip/hip_bf16.h>
#include <stdint.h>

// GraphTripleConv: B=32, O=4096, T=16384, D=H=DOUT=128
// out = [new_obj (B*O*128) | new_p (B*T*128)], f32
#define Bn 32
#define On 4096
#define Tn 16384
#define Dn 128

typedef short short8 __attribute__((ext_vector_type(8)));
typedef float f32x4 __attribute__((ext_vector_type(4)));

__device__ inline short f2bf(float f) {
  union { float f; uint32_t u; } v; v.f = f;
  uint32_t u = v.u;
  uint32_t r = u + 0x7fffu + ((u >> 16) & 1u);  // RNE
  return (short)(r >> 16);
}
__device__ inline float bf2f(unsigned short u) {
  union { uint32_t ui; float f; } cv; cv.ui = ((uint32_t)u) << 16; return cv.f;
}

// ---- weight prep: f32 [K][N] -> bf16 [N][K] (transposed, linear rows for coalesced LDS staging)
__global__ void prep_weights(const float* __restrict__ W1, const float* __restrict__ W2,
                             const float* __restrict__ W3, const float* __restrict__ W4,
                             short* __restrict__ w1t, short* __restrict__ w2t,
                             short* __restrict__ w3t, short* __restrict__ w4t) {
  int i = blockIdx.x * 256 + threadIdx.x;
  if (i < 49152) {
    int n = i / 384, k = i % 384;
    w1t[i] = f2bf(W1[k * 128 + n]);
  } else if (i < 49152 + 32768) {
    int j = i - 49152;
    int n = j / 128, k = j % 128;
    w2t[j] = f2bf(W2[k * 384 + 128 + n]);   // only cols 128..383 live (new_s dead)
  } else if (i < 49152 + 32768 + 16384) {
    int j = i - 81920;
    int n = j / 128, k = j % 128;
    w3t[j] = f2bf(W3[k * 128 + n]);
  } else if (i < 114688) {
    int j = i - 98304;
    int n = j / 128, k = j % 128;
    w4t[j] = f2bf(W4[k * 128 + n]);
  }
}

// ---- counting-sort index build: hist -> per-batch exclusive scan -> scatter ids
__global__ void hist_kernel(const int* __restrict__ edges, int* __restrict__ hist) {
  int tid = blockIdx.x * 256 + threadIdx.x;   // 0..B*T-1
  int b = tid >> 14;
  int o = edges[tid * 2 + 1];
  atomicAdd(&hist[b * On + o], 1);
}

__global__ void scan_kernel(const int* __restrict__ hist, int* __restrict__ offs) {
  __shared__ int sdata[1024];
  int b = blockIdx.x;
  int i = threadIdx.x;
  int base = b * On;
  int h[4]; int s = 0;
#pragma unroll
  for (int j = 0; j < 4; j++) { h[j] = hist[base + i * 4 + j]; s += h[j]; }
  sdata[i] = s;
  int tsum = s;
  for (int off = 1; off < 1024; off <<= 1) {
    __syncthreads();
    int t = (i >= off) ? sdata[i - off] : 0;
    __syncthreads();
    sdata[i] += t;
  }
  __syncthreads();
  int excl = sdata[i] - tsum + b * Tn;   // global edge position base
#pragma unroll
  for (int j = 0; j < 4; j++) { offs[base + i * 4 + j] = excl; excl += h[j]; }
}

__global__ void scatter_kernel(const int* __restrict__ edges, const int* __restrict__ offs,
                               int* __restrict__ fill, unsigned short* __restrict__ eidx) {
  int tid = blockIdx.x * 256 + threadIdx.x;
  int b = tid >> 14, t = tid & 16383;
  int o = edges[tid * 2 + 1];
  int pos = offs[b * On + o] + atomicAdd(&fill[b * On + o], 1);
  eidx[pos] = (unsigned short)t;
}

// ---- edge MLP v4: fully LDS-tiled GEMM.
// M=64 rows/block, 512 threads (8 waves: 2M x 4N).
// GEMM1 (K=384,N=128): A-tile 48KB staged once; w1 staged in 3 K-chunks of 32KB.
// GEMM2 (K=128,N=256): h1 16KB (reuses A region) + w2 64KB staged once.
// All K-loop operand reads are LDS (XOR-swizzled, conflict-free).
#define AS_OFF   0        // A tile: 64 rows x 768B (384 bf16)    [0, 49152)
#define WS_OFF   49152    // w1 chunk: 128 rows x 256B            [49152, 81920)
#define H1_OFF   0        // h1: 64 rows x 256B                   [0, 16384)
#define W2_OFF   16384    // w2: 256 rows x 256B                  [16384, 81920)

__global__ __launch_bounds__(512, 4) void edge_mlp(
    const float* __restrict__ obj, const float* __restrict__ pred,
    const int* __restrict__ edges,
    const short* __restrict__ w1t, const short* __restrict__ w2t,
    const float* __restrict__ b1, const float* __restrict__ g1, const float* __restrict__ be1,
    const float* __restrict__ b2, const float* __restrict__ g2, const float* __restrict__ be2,
    float* __restrict__ out_p, short* __restrict__ o_scr)
{
  __shared__ __align__(16) char lds[81920];

  const float invs = 1.0f / sqrtf(1.001f);   // 1/sqrt(1+EPS)
  int blk = blockIdx.x;
  int b = blk >> 8;                 // 256 blocks per batch (16384/64)
  int t0 = (blk & 255) << 6;
  int tid = threadIdx.x;

  // ---- stage gathered A rows as bf16 (8 threads/row, 48 elems each)
  {
    int r = tid >> 3, seg = tid & 7;
    int t = t0 + r;
    int e = (b * Tn + t) * 2;
    int sidx = edges[e], oidx = edges[e + 1];
    const float* srow = obj + (size_t)(b * On + sidx) * Dn;
    const float* prow = pred + (size_t)(b * Tn + t) * Dn;
    const float* orow = obj + (size_t)(b * On + oidx) * Dn;
#pragma unroll
    for (int i = 0; i < 6; i++) {
      int k = seg * 48 + i * 8;     // 8-groups never straddle the 128-boundaries
      const float* src = (k < 128) ? (srow + k) : (k < 256 ? prow + (k - 128) : orow + (k - 256));
      float4 v0 = *(const float4*)(src);
      float4 v1 = *(const float4*)(src + 4);
      short8 pk;
      pk[0]=f2bf(v0.x); pk[1]=f2bf(v0.y); pk[2]=f2bf(v0.z); pk[3]=f2bf(v0.w);
      pk[4]=f2bf(v1.x); pk[5]=f2bf(v1.y); pk[6]=f2bf(v1.z); pk[7]=f2bf(v1.w);
      *(short8*)(lds + AS_OFF + r * 768 + ((k * 2) ^ ((r & 7) << 4))) = pk;
    }
  }
  // ---- stage w1 chunk 0 (coalesced: 128 rows x 256B, 4 threads/row)
  {
    int n = tid >> 2, q = tid & 3;
    const short* src = w1t + n * 384 + q * 32;   // chunk 0: k in [0,128)
#pragma unroll
    for (int i = 0; i < 4; i++) {
      short8 v = *(const short8*)(src + i * 8);
      *(short8*)(lds + WS_OFF + n * 256 + ((q * 64 + i * 16) ^ ((n & 7) << 4))) = v;
    }
  }
  __syncthreads();

  int wave = tid >> 6, lane = tid & 63;
  int l15 = lane & 15, l4 = lane >> 4;
  int mg = wave >> 2;               // 2 row-groups of 32
  int ng = wave & 3;                // 4 col-groups

  // ---- GEMM1: 64x384 @ 384x128 ; wave: 32 rows x 32 cols
  f32x4 acc1[2][2] = {};
  for (int kc = 0; kc < 3; kc++) {
#pragma unroll
    for (int kk = 0; kk < 4; kk++) {
      short8 a[2], bb[2];
#pragma unroll
      for (int m = 0; m < 2; m++) {
        int row = mg * 32 + m * 16 + l15;
        a[m] = *(short8*)(lds + AS_OFF + row * 768 + ((kc * 256 + kk * 64 + 16 * l4) ^ ((row & 7) << 4)));
      }
#pragma unroll
      for (int n = 0; n < 2; n++) {
        int nr = ng * 32 + n * 16 + l15;
        bb[n] = *(short8*)(lds + WS_OFF + nr * 256 + ((kk * 64 + 16 * l4) ^ ((nr & 7) << 4)));
      }
#pragma unroll
      for (int m = 0; m < 2; m++)
#pragma unroll
        for (int n = 0; n < 2; n++)
          acc1[m][n] = __builtin_amdgcn_mfma_f32_16x16x32_bf16(a[m], bb[n], acc1[m][n], 0, 0, 0);
    }
    if (kc < 2) {
      __syncthreads();
      int n = tid >> 2, q = tid & 3;
      const short* src = w1t + n * 384 + (kc + 1) * 128 + q * 32;
#pragma unroll
      for (int i = 0; i < 4; i++) {
        short8 v = *(const short8*)(src + i * 8);
        *(short8*)(lds + WS_OFF + n * 256 + ((q * 64 + i * 16) ^ ((n & 7) << 4))) = v;
      }
      __syncthreads();
    }
  }
  __syncthreads();   // all reads of As/Ws done before h1/w2 overwrite

  // ---- h1 epilogue (affine+relu -> bf16, swizzled) + stage w2 (64KB, 2 threads/row)
#pragma unroll
  for (int n = 0; n < 2; n++) {
    int col = ng * 32 + n * 16 + l15;
    float gs = g1[col] * invs;
    float add = b1[col] * gs + be1[col];
#pragma unroll
    for (int m = 0; m < 2; m++)
#pragma unroll
      for (int rr = 0; rr < 4; rr++) {
        int row = mg * 32 + m * 16 + l4 * 4 + rr;
        float v = fmaxf(acc1[m][n][rr] * gs + add, 0.0f);
        *(short*)(lds + H1_OFF + row * 256 + ((col * 2) ^ ((row & 7) << 4))) = f2bf(v);
      }
  }
  {
    int n = tid >> 1, q = tid & 1;
    const short* src = w2t + n * 128 + q * 64;
#pragma unroll
    for (int i = 0; i < 8; i++) {
      short8 v = *(const short8*)(src + i * 8);
      *(short8*)(lds + W2_OFF + n * 256 + ((q * 128 + i * 16) ^ ((n & 7) << 4))) = v;
    }
  }
  __syncthreads();

  // ---- GEMM2: 64x128 @ 128x256 ; wave: 32 rows x 64 cols
  f32x4 acc2[2][4] = {};
#pragma unroll
  for (int kk = 0; kk < 4; kk++) {
    short8 a[2], bb[4];
#pragma unroll
    for (int m = 0; m < 2; m++) {
      int row = mg * 32 + m * 16 + l15;
      a[m] = *(short8*)(lds + H1_OFF + row * 256 + ((kk * 64 + 16 * l4) ^ ((row & 7) << 4)));
    }
#pragma unroll
    for (int n = 0; n < 4; n++) {
      int nr = ng * 64 + n * 16 + l15;
      bb[n] = *(short8*)(lds + W2_OFF + nr * 256 + ((kk * 64 + 16 * l4) ^ ((nr & 7) << 4)));
    }
#pragma unroll
    for (int m = 0; m < 2; m++)
#pragma unroll
      for (int n = 0; n < 4; n++)
        acc2[m][n] = __builtin_amdgcn_mfma_f32_16x16x32_bf16(a[m], bb[n], acc2[m][n], 0, 0, 0);
  }
  // epilogue: cols 0..127 -> new_p (f32); cols 128..255 -> o_scr (bf16)
#pragma unroll
  for (int n = 0; n < 4; n++) {
    int colp = ng * 64 + n * 16 + l15;   // 0..255
    int c2 = 128 + colp;                 // original W2 output column
    float gs = g2[c2] * invs;
    float add = b2[c2] * gs + be2[c2];
#pragma unroll
    for (int m = 0; m < 2; m++)
#pragma unroll
      for (int rr = 0; rr < 4; rr++) {
        int row = mg * 32 + m * 16 + l4 * 4 + rr;
        if (colp < 128) {
          out_p[(size_t)(b * Tn + t0 + row) * 128 + colp] =
              fmaxf(acc2[m][n][rr] * gs + add, 0.0f);
        } else {
          ((unsigned short*)o_scr)[(size_t)(b * Tn + t0 + row) * 128 + (colp - 128)] =
              (unsigned short)f2bf(fmaxf(acc2[m][n][rr] * gs + add, 0.0f));
        }
      }
  }
}

// ---- object MLP (pooling fused): gather-mean each obj's edge segment from o_scr,
// then GEMM3(128x128) -> GEMM4(128x128); writes new_obj.
__global__ __launch_bounds__(256) void obj_mlp(
    const short* __restrict__ o_scr, const int* __restrict__ hist,
    const int* __restrict__ offs, const unsigned short* __restrict__ eidx,
    float* __restrict__ out_obj,
    const short* __restrict__ w3t, const short* __restrict__ w4t,
    const float* __restrict__ b3, const float* __restrict__ g3, const float* __restrict__ be3,
    const float* __restrict__ b4, const float* __restrict__ g4, const float* __restrict__ be4)
{
  __shared__ short xs[64][136];
  __shared__ short hs[64][136];
  const float invs = 1.0f / sqrtf(1.001f);
  int row0 = blockIdx.x * 64;
  int tid = threadIdx.x;

  // ---- pooled gather: 4 threads/row, 32 cols each; mean over edge segment
  {
    int r = tid >> 2, seg = tid & 3;
    int rg = row0 + r;
    int bb_ = rg >> 12;                 // On = 4096 rows per batch
    int cnt = hist[rg], start = offs[rg];
    float sum[32];
#pragma unroll
    for (int j = 0; j < 32; j++) sum[j] = 0.f;
    for (int k = 0; k < cnt; k++) {
      int t = eidx[start + k];
      const unsigned short* src = (const unsigned short*)o_scr +
          ((size_t)(bb_ * Tn + t)) * 128 + seg * 32;
#pragma unroll
      for (int i = 0; i < 4; i++) {
        short8 v = *(const short8*)(src + i * 8);
#pragma unroll
        for (int j = 0; j < 8; j++) sum[i * 8 + j] += bf2f((unsigned short)v[j]);
      }
    }
    float ic = 1.0f / fmaxf((float)cnt, 1.0f);
#pragma unroll
    for (int i = 0; i < 4; i++) {
      short8 pk;
#pragma unroll
      for (int j = 0; j < 8; j++) pk[j] = f2bf(sum[i * 8 + j] * ic);
      *(short8*)&xs[r][seg * 32 + i * 8] = pk;
    }
  }
  __syncthreads();

  int wave = tid >> 6, lane = tid & 63;
  int l15 = lane & 15, l4 = lane >> 4;
  int n0 = wave * 32;

  f32x4 acc[4][2] = {};
  for (int kk = 0; kk < 4; kk++) {
    int k0 = kk * 32;
    short8 a[4], bb[2];
#pragma unroll
    for (int m = 0; m < 4; m++) a[m] = *(short8*)&xs[m * 16 + l15][k0 + 8 * l4];
#pragma unroll
    for (int n = 0; n < 2; n++) bb[n] = *(const short8*)&w3t[(n0 + n * 16 + l15) * 128 + k0 + 8 * l4];
#pragma unroll
    for (int m = 0; m < 4; m++)
#pragma unroll
      for (int n = 0; n < 2; n++)
        acc[m][n] = __builtin_amdgcn_mfma_f32_16x16x32_bf16(a[m], bb[n], acc[m][n], 0, 0, 0);
  }
#pragma unroll
  for (int n = 0; n < 2; n++) {
    int col = n0 + n * 16 + l15;
    float gs = g3[col] * invs;
    float add = b3[col] * gs + be3[col];
#pragma unroll
    for (int m = 0; m < 4; m++)
#pragma unroll
      for (int rr = 0; rr < 4; rr++) {
        float v = fmaxf(acc[m][n][rr] * gs + add, 0.0f);
        hs[m * 16 + l4 * 4 + rr][col] = f2bf(v);
      }
  }
  __syncthreads();

  f32x4 acc2[4][2] = {};
  for (int kk = 0; kk < 4; kk++) {
    int k0 = kk * 32;
    short8 a[4], bb[2];
#pragma unroll
    for (int m = 0; m < 4; m++) a[m] = *(short8*)&hs[m * 16 + l15][k0 + 8 * l4];
#pragma unroll
    for (int n = 0; n < 2; n++) bb[n] = *(const short8*)&w4t[(n0 + n * 16 + l15) * 128 + k0 + 8 * l4];
#pragma unroll
    for (int m = 0; m < 4; m++)
#pragma unroll
      for (int n = 0; n < 2; n++)
        acc2[m][n] = __builtin_amdgcn_mfma_f32_16x16x32_bf16(a[m], bb[n], acc2[m][n], 0, 0, 0);
  }
#pragma unroll
  for (int n = 0; n < 2; n++) {
    int col = n0 + n * 16 + l15;
    float gs = g4[col] * invs;
    float add = b4[col] * gs + be4[col];
#pragma unroll
    for (int m = 0; m < 4; m++)
#pragma unroll
      for (int rr = 0; rr < 4; rr++) {
        int row = m * 16 + l4 * 4 + rr;
        float v = fmaxf(acc2[m][n][rr] * gs + add, 0.0f);
        out_obj[(size_t)(row0 + row) * 128 + col] = v;
      }
  }
}

extern "C" void kernel_launch(void* const* d_in, const int* in_sizes, int n_in,
                              void* d_out, int out_size, void* d_ws, size_t ws_size,
                              hipStream_t stream) {
  const float* obj  = (const float*)d_in[0];
  const float* pred = (const float*)d_in[1];
  const int*   edges= (const int*)d_in[2];
  const float* W1 = (const float*)d_in[3];
  const float* b1 = (const float*)d_in[4];
  const float* g1 = (const float*)d_in[5];
  const float* be1= (const float*)d_in[6];
  const float* W2 = (const float*)d_in[7];
  const float* b2 = (const float*)d_in[8];
  const float* g2 = (const float*)d_in[9];
  const float* be2= (const float*)d_in[10];
  const float* W3 = (const float*)d_in[11];
  const float* b3 = (const float*)d_in[12];
  const float* g3 = (const float*)d_in[13];
  const float* be3= (const float*)d_in[14];
  const float* W4 = (const float*)d_in[15];
  const float* b4 = (const float*)d_in[16];
  const float* g4 = (const float*)d_in[17];
  const float* be4= (const float*)d_in[18];

  float* out_obj = (float*)d_out;                           // B*O*128
  float* out_p   = (float*)d_out + (size_t)Bn * On * 128;   // B*T*128

  char* ws = (char*)d_ws;
  // weights at [0, 256KB)
  short* w1t = (short*)(ws);
  short* w2t = (short*)(ws + 49152 * 2);
  short* w3t = (short*)(ws + (49152 + 32768) * 2);
  short* w4t = (short*)(ws + (49152 + 32768 + 16384) * 2);

  const size_t OFF_HIST = 262144;                 // int B*O = 512 KB
  const size_t OFF_OFFS = OFF_HIST + 524288;
  const size_t OFF_FILL = OFF_OFFS + 524288;
  const size_t OFF_EIDX = OFF_FILL + 524288;      // u16 B*T = 1 MB
  const size_t OFF_OSCR = 4194304;                // bf16 B*T*128 = 128 MiB

  int* hist = (int*)(ws + OFF_HIST);
  int* offs = (int*)(ws + OFF_OFFS);
  int* fill = (int*)(ws + OFF_FILL);
  unsigned short* eidx = (unsigned short*)(ws + OFF_EIDX);
  short* o_scr = (short*)(ws + OFF_OSCR);

  hipMemsetAsync(hist, 0, 524288, stream);
  hipMemsetAsync(fill, 0, 524288, stream);

  prep_weights<<<448, 256, 0, stream>>>(W1, W2, W3, W4, w1t, w2t, w3t, w4t);
  hist_kernel<<<(Bn * Tn) / 256, 256, 0, stream>>>(edges, hist);
  scan_kernel<<<Bn, 1024, 0, stream>>>(hist, offs);
  scatter_kernel<<<(Bn * Tn) / 256, 256, 0, stream>>>(edges, offs, fill, eidx);
  edge_mlp<<<Bn * (Tn / 64), 512, 0, stream>>>(obj, pred, edges, w1t, w2t,
      b1, g1, be1, b2, g2, be2, out_p, o_scr);
  obj_mlp<<<(Bn * On) / 64, 256, 0, stream>>>(o_scr, hist, offs, eidx, out_obj,
      w3t, w4t, b3, g3, be3, b4, g4, be4);
}

// Round 5
// 347.517 us; speedup vs baseline: 2.2507x; 1.3905x over previous
//
#include <hip/hip_runtime.h>
#include <hip/hip_bf16.h>
#include <stdint.h>

// GraphTripleConv: B=32, O=4096, T=16384, D=H=DOUT=128
// out = [new_obj (B*O*128) | new_p (B*T*128)], f32
#define Bn 32
#define On 4096
#define Tn 16384
#define Dn 128

typedef short short8 __attribute__((ext_vector_type(8)));
typedef float f32x4 __attribute__((ext_vector_type(4)));

__device__ inline short f2bf(float f) {
  union { float f; uint32_t u; } v; v.f = f;
  uint32_t u = v.u;
  uint32_t r = u + 0x7fffu + ((u >> 16) & 1u);  // RNE
  return (short)(r >> 16);
}
__device__ inline float bf2f(unsigned short u) {
  union { uint32_t ui; float f; } cv; cv.ui = ((uint32_t)u) << 16; return cv.f;
}

// ---- weight prep: f32 [K][N] -> bf16 [N][K] (transposed)
__global__ void prep_weights(const float* __restrict__ W1, const float* __restrict__ W2,
                             const float* __restrict__ W3, const float* __restrict__ W4,
                             short* __restrict__ w1t, short* __restrict__ w2t,
                             short* __restrict__ w3t, short* __restrict__ w4t) {
  int i = blockIdx.x * 256 + threadIdx.x;
  if (i < 49152) {
    int n = i / 384, k = i % 384;
    w1t[i] = f2bf(W1[k * 128 + n]);
  } else if (i < 49152 + 32768) {
    int j = i - 49152;
    int n = j / 128, k = j % 128;
    w2t[j] = f2bf(W2[k * 384 + 128 + n]);   // only cols 128..383 live (new_s dead)
  } else if (i < 49152 + 32768 + 16384) {
    int j = i - 81920;
    int n = j / 128, k = j % 128;
    w3t[j] = f2bf(W3[k * 128 + n]);
  } else if (i < 114688) {
    int j = i - 98304;
    int n = j / 128, k = j % 128;
    w4t[j] = f2bf(W4[k * 128 + n]);
  }
}

// ---- counting-sort index build
__global__ void hist_kernel(const int* __restrict__ edges, int* __restrict__ hist) {
  int tid = blockIdx.x * 256 + threadIdx.x;
  int b = tid >> 14;
  int o = edges[tid * 2 + 1];
  atomicAdd(&hist[b * On + o], 1);
}

__global__ void scan_kernel(const int* __restrict__ hist, int* __restrict__ offs) {
  __shared__ int sdata[1024];
  int b = blockIdx.x;
  int i = threadIdx.x;
  int base = b * On;
  int h[4]; int s = 0;
#pragma unroll
  for (int j = 0; j < 4; j++) { h[j] = hist[base + i * 4 + j]; s += h[j]; }
  sdata[i] = s;
  int tsum = s;
  for (int off = 1; off < 1024; off <<= 1) {
    __syncthreads();
    int t = (i >= off) ? sdata[i - off] : 0;
    __syncthreads();
    sdata[i] += t;
  }
  __syncthreads();
  int excl = sdata[i] - tsum + b * Tn;
#pragma unroll
  for (int j = 0; j < 4; j++) { offs[base + i * 4 + j] = excl; excl += h[j]; }
}

__global__ void scatter_kernel(const int* __restrict__ edges, const int* __restrict__ offs,
                               int* __restrict__ fill, unsigned short* __restrict__ eidx) {
  int tid = blockIdx.x * 256 + threadIdx.x;
  int b = tid >> 14, t = tid & 16383;
  int o = edges[tid * 2 + 1];
  int pos = offs[b * On + o] + atomicAdd(&fill[b * On + o], 1);
  eidx[pos] = (unsigned short)t;
}

// ---- object projection: objSO[r] = [ obj[r] @ W1s (128) | obj[r] @ W1o (128) ], bf16
// M=64 rows/block, 512 threads (8 waves: 2 mg x 4 ng). LDS: A 16KB + W chunk 32KB.
#define PA_OFF 0
#define PW_OFF 16384
__global__ __launch_bounds__(512, 4) void objproj(
    const float* __restrict__ obj, const short* __restrict__ w1t,
    unsigned short* __restrict__ objSO)
{
  __shared__ __align__(16) char lds[49152];
  int tid = threadIdx.x;
  int row0 = blockIdx.x * 64;

  // stage A: 8 thr/row, 16 f32 each -> bf16 swizzled
  {
    int r = tid >> 3, seg = tid & 7;
    const float* src = obj + (size_t)(row0 + r) * Dn + seg * 16;
    float4 v0 = *(const float4*)(src);
    float4 v1 = *(const float4*)(src + 4);
    float4 v2 = *(const float4*)(src + 8);
    float4 v3 = *(const float4*)(src + 12);
    short8 p0, p1;
    p0[0]=f2bf(v0.x); p0[1]=f2bf(v0.y); p0[2]=f2bf(v0.z); p0[3]=f2bf(v0.w);
    p0[4]=f2bf(v1.x); p0[5]=f2bf(v1.y); p0[6]=f2bf(v1.z); p0[7]=f2bf(v1.w);
    p1[0]=f2bf(v2.x); p1[1]=f2bf(v2.y); p1[2]=f2bf(v2.z); p1[3]=f2bf(v2.w);
    p1[4]=f2bf(v3.x); p1[5]=f2bf(v3.y); p1[6]=f2bf(v3.z); p1[7]=f2bf(v3.w);
    int swz = (r & 7) << 4;
    *(short8*)(lds + PA_OFF + r * 256 + ((seg * 32) ^ swz)) = p0;
    *(short8*)(lds + PA_OFF + r * 256 + ((seg * 32 + 16) ^ swz)) = p1;
  }
  int wave = tid >> 6, lane = tid & 63;
  int l15 = lane & 15, l4 = lane >> 4;
  int mg = wave >> 2, ng = wave & 3;

#pragma unroll
  for (int half = 0; half < 2; half++) {
    // stage weight chunk: W1s (k 0..127) or W1o (k 256..383); rows n = live output col
    if (half) __syncthreads();   // wait GEMM reads of previous chunk
    {
      int n = tid >> 2, q = tid & 3;
      const short* src = w1t + n * 384 + half * 256 + q * 32;
      int swz = (n & 7) << 4;
#pragma unroll
      for (int i = 0; i < 4; i++) {
        short8 v = *(const short8*)(src + i * 8);
        *(short8*)(lds + PW_OFF + n * 256 + ((q * 64 + i * 16) ^ swz)) = v;
      }
    }
    __syncthreads();
    f32x4 acc[2][2] = {};
#pragma unroll
    for (int kk = 0; kk < 4; kk++) {
      short8 a[2], bb[2];
#pragma unroll
      for (int m = 0; m < 2; m++) {
        int row = mg * 32 + m * 16 + l15;
        a[m] = *(short8*)(lds + PA_OFF + row * 256 + ((kk * 64 + 16 * l4) ^ ((row & 7) << 4)));
      }
#pragma unroll
      for (int n = 0; n < 2; n++) {
        int nr = ng * 32 + n * 16 + l15;
        bb[n] = *(short8*)(lds + PW_OFF + nr * 256 + ((kk * 64 + 16 * l4) ^ ((nr & 7) << 4)));
      }
#pragma unroll
      for (int m = 0; m < 2; m++)
#pragma unroll
        for (int n = 0; n < 2; n++)
          acc[m][n] = __builtin_amdgcn_mfma_f32_16x16x32_bf16(a[m], bb[n], acc[m][n], 0, 0, 0);
    }
    // raw bf16 store (no bias/affine here)
#pragma unroll
    for (int n = 0; n < 2; n++) {
      int col = ng * 32 + n * 16 + l15;
#pragma unroll
      for (int m = 0; m < 2; m++)
#pragma unroll
        for (int rr = 0; rr < 4; rr++) {
          int row = mg * 32 + m * 16 + l4 * 4 + rr;
          objSO[(size_t)(row0 + row) * 256 + half * 128 + col] =
              (unsigned short)f2bf(acc[m][n][rr]);
        }
    }
  }
}

// ---- edge MLP v5: A = pred tile (contiguous); h = relu(aff(pred@W1p + objS[s]+objO[o]))
// then GEMM2 (K=128, N=256). M=64, 512 thr. LDS 64.5KB -> 2 blocks/CU.
#define EA_OFF 0        // A / h1: 64 x 256B (bf16, XOR-swizzled)
#define EG_OFF 16384    // g = objS[s]+objO[o]: 64 x 264B (bf16, padded stride)
#define EW_OFF 33280    // weight chunk: 128 x 256B (swizzled)
__global__ __launch_bounds__(512, 4) void edge_mlp(
    const float* __restrict__ pred, const int* __restrict__ edges,
    const unsigned short* __restrict__ objSO,
    const short* __restrict__ w1t, const short* __restrict__ w2t,
    const float* __restrict__ b1, const float* __restrict__ g1, const float* __restrict__ be1,
    const float* __restrict__ b2, const float* __restrict__ g2, const float* __restrict__ be2,
    float* __restrict__ out_p, unsigned short* __restrict__ o_scr)
{
  __shared__ __align__(16) char lds[66048];

  const float invs = 1.0f / sqrtf(1.001f);
  int blk = blockIdx.x;
  int b = blk >> 8;                 // 256 blocks per batch
  int t0 = (blk & 255) << 6;
  int tid = threadIdx.x;

  // ---- stage phase: edges -> A(pred) -> w1p -> g(objS[s]+objO[o])
  {
    int r = tid >> 3, seg = tid & 7;
    int t = t0 + r;
    int2 e = *(const int2*)&edges[(size_t)(b * Tn + t) * 2];

    // A: pred tile, 16 f32 per thread, contiguous
    const float* src = pred + (size_t)(b * Tn + t) * Dn + seg * 16;
    float4 v0 = *(const float4*)(src);
    float4 v1 = *(const float4*)(src + 4);
    float4 v2 = *(const float4*)(src + 8);
    float4 v3 = *(const float4*)(src + 12);

    // w1p chunk: rows n, k in [128,256) of w1t
    int wn = tid >> 2, wq = tid & 3;
    const short* wsrc = w1t + wn * 384 + 128 + wq * 32;
    short8 w0 = *(const short8*)(wsrc);
    short8 w1_ = *(const short8*)(wsrc + 8);
    short8 w2_ = *(const short8*)(wsrc + 16);
    short8 w3_ = *(const short8*)(wsrc + 24);

    // g: two 32B bf16 segments from objSO (random rows, L2/L3)
    const unsigned short* srow = objSO + (size_t)(b * On + e.x) * 256 + seg * 16;
    const unsigned short* orow = objSO + (size_t)(b * On + e.y) * 256 + 128 + seg * 16;
    short8 s0 = *(const short8*)(srow);
    short8 s1 = *(const short8*)(srow + 8);
    short8 o0 = *(const short8*)(orow);
    short8 o1 = *(const short8*)(orow + 8);

    int swz = (r & 7) << 4;
    short8 p0, p1;
    p0[0]=f2bf(v0.x); p0[1]=f2bf(v0.y); p0[2]=f2bf(v0.z); p0[3]=f2bf(v0.w);
    p0[4]=f2bf(v1.x); p0[5]=f2bf(v1.y); p0[6]=f2bf(v1.z); p0[7]=f2bf(v1.w);
    p1[0]=f2bf(v2.x); p1[1]=f2bf(v2.y); p1[2]=f2bf(v2.z); p1[3]=f2bf(v2.w);
    p1[4]=f2bf(v3.x); p1[5]=f2bf(v3.y); p1[6]=f2bf(v3.z); p1[7]=f2bf(v3.w);
    *(short8*)(lds + EA_OFF + r * 256 + ((seg * 32) ^ swz)) = p0;
    *(short8*)(lds + EA_OFF + r * 256 + ((seg * 32 + 16) ^ swz)) = p1;

    int wswz = (wn & 7) << 4;
    *(short8*)(lds + EW_OFF + wn * 256 + ((wq * 64) ^ wswz)) = w0;
    *(short8*)(lds + EW_OFF + wn * 256 + ((wq * 64 + 16) ^ wswz)) = w1_;
    *(short8*)(lds + EW_OFF + wn * 256 + ((wq * 64 + 32) ^ wswz)) = w2_;
    *(short8*)(lds + EW_OFF + wn * 256 + ((wq * 64 + 48) ^ wswz)) = w3_;

    short8 g0, g1v;
#pragma unroll
    for (int j = 0; j < 8; j++) {
      g0[j]  = f2bf(bf2f((unsigned short)s0[j]) + bf2f((unsigned short)o0[j]));
      g1v[j] = f2bf(bf2f((unsigned short)s1[j]) + bf2f((unsigned short)o1[j]));
    }
    *(short8*)(lds + EG_OFF + r * 264 + seg * 32) = g0;
    *(short8*)(lds + EG_OFF + r * 264 + seg * 32 + 16) = g1v;
  }
  __syncthreads();

  int wave = tid >> 6, lane = tid & 63;
  int l15 = lane & 15, l4 = lane >> 4;
  int mg = wave >> 2, ng = wave & 3;

  // ---- GEMM1: 64x128 @ 128x128 (pred @ W1p); wave tile 32x32
  f32x4 acc1[2][2] = {};
#pragma unroll
  for (int kk = 0; kk < 4; kk++) {
    short8 a[2], bb[2];
#pragma unroll
    for (int m = 0; m < 2; m++) {
      int row = mg * 32 + m * 16 + l15;
      a[m] = *(short8*)(lds + EA_OFF + row * 256 + ((kk * 64 + 16 * l4) ^ ((row & 7) << 4)));
    }
#pragma unroll
    for (int n = 0; n < 2; n++) {
      int nr = ng * 32 + n * 16 + l15;
      bb[n] = *(short8*)(lds + EW_OFF + nr * 256 + ((kk * 64 + 16 * l4) ^ ((nr & 7) << 4)));
    }
#pragma unroll
    for (int m = 0; m < 2; m++)
#pragma unroll
      for (int n = 0; n < 2; n++)
        acc1[m][n] = __builtin_amdgcn_mfma_f32_16x16x32_bf16(a[m], bb[n], acc1[m][n], 0, 0, 0);
  }
  __syncthreads();   // A & w1p reads done

  // ---- epilogue1: h1 = relu((acc1 + g)*gs + add) -> bf16 LDS (overwrites A)
  //      + stage w2 chunk0 (rows 0..127)
#pragma unroll
  for (int n = 0; n < 2; n++) {
    int col = ng * 32 + n * 16 + l15;
    float gs = g1[col] * invs;
    float add = b1[col] * gs + be1[col];
#pragma unroll
    for (int m = 0; m < 2; m++)
#pragma unroll
      for (int rr = 0; rr < 4; rr++) {
        int row = mg * 32 + m * 16 + l4 * 4 + rr;
        float gv = bf2f(*(const unsigned short*)(lds + EG_OFF + row * 264 + col * 2));
        float v = fmaxf((acc1[m][n][rr] + gv) * gs + add, 0.0f);
        *(short*)(lds + EA_OFF + row * 256 + ((col * 2) ^ ((row & 7) << 4))) = f2bf(v);
      }
  }
  {
    int n = tid >> 2, q = tid & 3;
    const short* src = w2t + n * 128 + q * 32;
    int swz = (n & 7) << 4;
#pragma unroll
    for (int i = 0; i < 4; i++) {
      short8 v = *(const short8*)(src + i * 8);
      *(short8*)(lds + EW_OFF + n * 256 + ((q * 64 + i * 16) ^ swz)) = v;
    }
  }
  __syncthreads();

  // ---- GEMM2 chunk0: h1 @ w2[0:128] -> new_p
  {
    f32x4 acc2[2][2] = {};
#pragma unroll
    for (int kk = 0; kk < 4; kk++) {
      short8 a[2], bb[2];
#pragma unroll
      for (int m = 0; m < 2; m++) {
        int row = mg * 32 + m * 16 + l15;
        a[m] = *(short8*)(lds + EA_OFF + row * 256 + ((kk * 64 + 16 * l4) ^ ((row & 7) << 4)));
      }
#pragma unroll
      for (int n = 0; n < 2; n++) {
        int nr = ng * 32 + n * 16 + l15;
        bb[n] = *(short8*)(lds + EW_OFF + nr * 256 + ((kk * 64 + 16 * l4) ^ ((nr & 7) << 4)));
      }
#pragma unroll
      for (int m = 0; m < 2; m++)
#pragma unroll
        for (int n = 0; n < 2; n++)
          acc2[m][n] = __builtin_amdgcn_mfma_f32_16x16x32_bf16(a[m], bb[n], acc2[m][n], 0, 0, 0);
    }
#pragma unroll
    for (int n = 0; n < 2; n++) {
      int colp = ng * 32 + n * 16 + l15;     // 0..127
      int c2 = 128 + colp;
      float gs = g2[c2] * invs;
      float add = b2[c2] * gs + be2[c2];
#pragma unroll
      for (int m = 0; m < 2; m++)
#pragma unroll
        for (int rr = 0; rr < 4; rr++) {
          int row = mg * 32 + m * 16 + l4 * 4 + rr;
          out_p[(size_t)(b * Tn + t0 + row) * 128 + colp] =
              fmaxf(acc2[m][n][rr] * gs + add, 0.0f);
        }
    }
  }
  __syncthreads();   // w2c0 reads done

  // ---- stage w2 chunk1 (rows 128..255)
  {
    int n = tid >> 2, q = tid & 3;
    const short* src = w2t + (128 + n) * 128 + q * 32;
    int swz = (n & 7) << 4;
#pragma unroll
    for (int i = 0; i < 4; i++) {
      short8 v = *(const short8*)(src + i * 8);
      *(short8*)(lds + EW_OFF + n * 256 + ((q * 64 + i * 16) ^ swz)) = v;
    }
  }
  __syncthreads();

  // ---- GEMM2 chunk1: h1 @ w2[128:256] -> o_scr (bf16)
  {
    f32x4 acc2[2][2] = {};
#pragma unroll
    for (int kk = 0; kk < 4; kk++) {
      short8 a[2], bb[2];
#pragma unroll
      for (int m = 0; m < 2; m++) {
        int row = mg * 32 + m * 16 + l15;
        a[m] = *(short8*)(lds + EA_OFF + row * 256 + ((kk * 64 + 16 * l4) ^ ((row & 7) << 4)));
      }
#pragma unroll
      for (int n = 0; n < 2; n++) {
        int nr = ng * 32 + n * 16 + l15;
        bb[n] = *(short8*)(lds + EW_OFF + nr * 256 + ((kk * 64 + 16 * l4) ^ ((nr & 7) << 4)));
      }
#pragma unroll
      for (int m = 0; m < 2; m++)
#pragma unroll
        for (int n = 0; n < 2; n++)
          acc2[m][n] = __builtin_amdgcn_mfma_f32_16x16x32_bf16(a[m], bb[n], acc2[m][n], 0, 0, 0);
    }
#pragma unroll
    for (int n = 0; n < 2; n++) {
      int colp = ng * 32 + n * 16 + l15;     // 0..127 within chunk1
      int c2 = 256 + colp;
      float gs = g2[c2] * invs;
      float add = b2[c2] * gs + be2[c2];
#pragma unroll
      for (int m = 0; m < 2; m++)
#pragma unroll
        for (int rr = 0; rr < 4; rr++) {
          int row = mg * 32 + m * 16 + l4 * 4 + rr;
          o_scr[(size_t)(b * Tn + t0 + row) * 128 + colp] =
              (unsigned short)f2bf(fmaxf(acc2[m][n][rr] * gs + add, 0.0f));
        }
    }
  }
}

// ---- object MLP (pooling fused): gather-mean from o_scr, GEMM3 -> GEMM4
__global__ __launch_bounds__(256) void obj_mlp(
    const unsigned short* __restrict__ o_scr, const int* __restrict__ hist,
    const int* __restrict__ offs, const unsigned short* __restrict__ eidx,
    float* __restrict__ out_obj,
    const short* __restrict__ w3t, const short* __restrict__ w4t,
    const float* __restrict__ b3, const float* __restrict__ g3, const float* __restrict__ be3,
    const float* __restrict__ b4, const float* __restrict__ g4, const float* __restrict__ be4)
{
  __shared__ short xs[64][136];
  __shared__ short hs[64][136];
  const float invs = 1.0f / sqrtf(1.001f);
  int row0 = blockIdx.x * 64;
  int tid = threadIdx.x;

  {
    int r = tid >> 2, seg = tid & 3;
    int rg = row0 + r;
    int bb_ = rg >> 12;
    int cnt = hist[rg], start = offs[rg];
    float sum[32];
#pragma unroll
    for (int j = 0; j < 32; j++) sum[j] = 0.f;
    for (int k = 0; k < cnt; k++) {
      int t = eidx[start + k];
      const unsigned short* src = o_scr + ((size_t)(bb_ * Tn + t)) * 128 + seg * 32;
#pragma unroll
      for (int i = 0; i < 4; i++) {
        short8 v = *(const short8*)(src + i * 8);
#pragma unroll
        for (int j = 0; j < 8; j++) sum[i * 8 + j] += bf2f((unsigned short)v[j]);
      }
    }
    float ic = 1.0f / fmaxf((float)cnt, 1.0f);
#pragma unroll
    for (int i = 0; i < 4; i++) {
      short8 pk;
#pragma unroll
      for (int j = 0; j < 8; j++) pk[j] = f2bf(sum[i * 8 + j] * ic);
      *(short8*)&xs[r][seg * 32 + i * 8] = pk;
    }
  }
  __syncthreads();

  int wave = tid >> 6, lane = tid & 63;
  int l15 = lane & 15, l4 = lane >> 4;
  int n0 = wave * 32;

  f32x4 acc[4][2] = {};
  for (int kk = 0; kk < 4; kk++) {
    int k0 = kk * 32;
    short8 a[4], bb[2];
#pragma unroll
    for (int m = 0; m < 4; m++) a[m] = *(short8*)&xs[m * 16 + l15][k0 + 8 * l4];
#pragma unroll
    for (int n = 0; n < 2; n++) bb[n] = *(const short8*)&w3t[(n0 + n * 16 + l15) * 128 + k0 + 8 * l4];
#pragma unroll
    for (int m = 0; m < 4; m++)
#pragma unroll
      for (int n = 0; n < 2; n++)
        acc[m][n] = __builtin_amdgcn_mfma_f32_16x16x32_bf16(a[m], bb[n], acc[m][n], 0, 0, 0);
  }
#pragma unroll
  for (int n = 0; n < 2; n++) {
    int col = n0 + n * 16 + l15;
    float gs = g3[col] * invs;
    float add = b3[col] * gs + be3[col];
#pragma unroll
    for (int m = 0; m < 4; m++)
#pragma unroll
      for (int rr = 0; rr < 4; rr++) {
        float v = fmaxf(acc[m][n][rr] * gs + add, 0.0f);
        hs[m * 16 + l4 * 4 + rr][col] = f2bf(v);
      }
  }
  __syncthreads();

  f32x4 acc2[4][2] = {};
  for (int kk = 0; kk < 4; kk++) {
    int k0 = kk * 32;
    short8 a[4], bb[2];
#pragma unroll
    for (int m = 0; m < 4; m++) a[m] = *(short8*)&hs[m * 16 + l15][k0 + 8 * l4];
#pragma unroll
    for (int n = 0; n < 2; n++) bb[n] = *(const short8*)&w4t[(n0 + n * 16 + l15) * 128 + k0 + 8 * l4];
#pragma unroll
    for (int m = 0; m < 4; m++)
#pragma unroll
      for (int n = 0; n < 2; n++)
        acc2[m][n] = __builtin_amdgcn_mfma_f32_16x16x32_bf16(a[m], bb[n], acc2[m][n], 0, 0, 0);
  }
#pragma unroll
  for (int n = 0; n < 2; n++) {
    int col = n0 + n * 16 + l15;
    float gs = g4[col] * invs;
    float add = b4[col] * gs + be4[col];
#pragma unroll
    for (int m = 0; m < 4; m++)
#pragma unroll
      for (int rr = 0; rr < 4; rr++) {
        int row = m * 16 + l4 * 4 + rr;
        float v = fmaxf(acc2[m][n][rr] * gs + add, 0.0f);
        out_obj[(size_t)(row0 + row) * 128 + col] = v;
      }
  }
}

extern "C" void kernel_launch(void* const* d_in, const int* in_sizes, int n_in,
                              void* d_out, int out_size, void* d_ws, size_t ws_size,
                              hipStream_t stream) {
  const float* obj  = (const float*)d_in[0];
  const float* pred = (const float*)d_in[1];
  const int*   edges= (const int*)d_in[2];
  const float* W1 = (const float*)d_in[3];
  const float* b1 = (const float*)d_in[4];
  const float* g1 = (const float*)d_in[5];
  const float* be1= (const float*)d_in[6];
  const float* W2 = (const float*)d_in[7];
  const float* b2 = (const float*)d_in[8];
  const float* g2 = (const float*)d_in[9];
  const float* be2= (const float*)d_in[10];
  const float* W3 = (const float*)d_in[11];
  const float* b3 = (const float*)d_in[12];
  const float* g3 = (const float*)d_in[13];
  const float* be3= (const float*)d_in[14];
  const float* W4 = (const float*)d_in[15];
  const float* b4 = (const float*)d_in[16];
  const float* g4 = (const float*)d_in[17];
  const float* be4= (const float*)d_in[18];

  float* out_obj = (float*)d_out;                           // B*O*128
  float* out_p   = (float*)d_out + (size_t)Bn * On * 128;   // B*T*128
  // objSO (bf16 B*O*256 = 67 MB) lives in the out_obj region (dead until obj_mlp)
  unsigned short* objSO = (unsigned short*)d_out;

  char* ws = (char*)d_ws;
  short* w1t = (short*)(ws);
  short* w2t = (short*)(ws + 49152 * 2);
  short* w3t = (short*)(ws + (49152 + 32768) * 2);
  short* w4t = (short*)(ws + (49152 + 32768 + 16384) * 2);

  const size_t OFF_HIST = 262144;
  const size_t OFF_OFFS = OFF_HIST + 524288;
  const size_t OFF_FILL = OFF_OFFS + 524288;
  const size_t OFF_EIDX = OFF_FILL + 524288;      // u16 B*T = 1 MB
  const size_t OFF_OSCR = 4194304;                // bf16 B*T*128 = 128 MiB

  int* hist = (int*)(ws + OFF_HIST);
  int* offs = (int*)(ws + OFF_OFFS);
  int* fill = (int*)(ws + OFF_FILL);
  unsigned short* eidx = (unsigned short*)(ws + OFF_EIDX);
  unsigned short* o_scr = (unsigned short*)(ws + OFF_OSCR);

  hipMemsetAsync(hist, 0, 524288, stream);
  hipMemsetAsync(fill, 0, 524288, stream);

  prep_weights<<<448, 256, 0, stream>>>(W1, W2, W3, W4, w1t, w2t, w3t, w4t);
  hist_kernel<<<(Bn * Tn) / 256, 256, 0, stream>>>(edges, hist);
  scan_kernel<<<Bn, 1024, 0, stream>>>(hist, offs);
  scatter_kernel<<<(Bn * Tn) / 256, 256, 0, stream>>>(edges, offs, fill, eidx);
  objproj<<<(Bn * On) / 64, 512, 0, stream>>>(obj, w1t, objSO);
  edge_mlp<<<Bn * (Tn / 64), 512, 0, stream>>>(pred, edges, objSO, w1t, w2t,
      b1, g1, be1, b2, g2, be2, out_p, o_scr);
  obj_mlp<<<(Bn * On) / 64, 256, 0, stream>>>(o_scr, hist, offs, eidx, out_obj,
      w3t, w4t, b3, g3, be3, b4, g4, be4);
}

// Round 6
// 309.146 us; speedup vs baseline: 2.5301x; 1.1241x over previous
//
#include <hip/hip_runtime.h>
#include <hip/hip_bf16.h>
#include <stdint.h>

// GraphTripleConv: B=32, O=4096, T=16384, D=H=DOUT=128
// out = [new_obj (B*O*128) | new_p (B*T*128)], f32
#define Bn 32
#define On 4096
#define Tn 16384
#define Dn 128

typedef short short8 __attribute__((ext_vector_type(8)));
typedef float f32x4 __attribute__((ext_vector_type(4)));

__device__ inline short f2bf(float f) {
  union { float f; uint32_t u; } v; v.f = f;
  uint32_t u = v.u;
  uint32_t r = u + 0x7fffu + ((u >> 16) & 1u);  // RNE
  return (short)(r >> 16);
}
__device__ inline float bf2f(unsigned short u) {
  union { uint32_t ui; float f; } cv; cv.ui = ((uint32_t)u) << 16; return cv.f;
}

// ---- weight prep: f32 [K][N] -> bf16 [N][K] (transposed)
__global__ void prep_weights(const float* __restrict__ W1, const float* __restrict__ W2,
                             const float* __restrict__ W3, const float* __restrict__ W4,
                             short* __restrict__ w1t, short* __restrict__ w2t,
                             short* __restrict__ w3t, short* __restrict__ w4t) {
  int i = blockIdx.x * 256 + threadIdx.x;
  if (i < 49152) {
    int n = i / 384, k = i % 384;
    w1t[i] = f2bf(W1[k * 128 + n]);
  } else if (i < 49152 + 32768) {
    int j = i - 49152;
    int n = j / 128, k = j % 128;
    w2t[j] = f2bf(W2[k * 384 + 128 + n]);   // only cols 128..383 live (new_s dead)
  } else if (i < 49152 + 32768 + 16384) {
    int j = i - 81920;
    int n = j / 128, k = j % 128;
    w3t[j] = f2bf(W3[k * 128 + n]);
  } else if (i < 114688) {
    int j = i - 98304;
    int n = j / 128, k = j % 128;
    w4t[j] = f2bf(W4[k * 128 + n]);
  }
}

// ---- fused counting sort: per-batch hist+scan+scatter entirely in LDS
__global__ __launch_bounds__(1024) void sort_kernel(
    const int* __restrict__ edges, int* __restrict__ hist_g,
    int* __restrict__ offs_g, unsigned short* __restrict__ eidx)
{
  __shared__ int h[4096];
  __shared__ int of[4096];
  __shared__ int sd[1024];
  int b = blockIdx.x, tid = threadIdx.x;
#pragma unroll
  for (int i = 0; i < 4; i++) h[tid + i * 1024] = 0;
  __syncthreads();
  int ov[16];
#pragma unroll
  for (int j = 0; j < 16; j++) {
    int t = j * 1024 + tid;
    ov[j] = edges[((size_t)(b * Tn + t)) * 2 + 1];
    atomicAdd(&h[ov[j]], 1);
  }
  __syncthreads();
  int base = tid * 4;
  int hh[4]; int s = 0;
#pragma unroll
  for (int j = 0; j < 4; j++) { hh[j] = h[base + j]; s += hh[j]; }
  sd[tid] = s;
  int tsum = s;
  for (int off = 1; off < 1024; off <<= 1) {
    __syncthreads();
    int t = (tid >= off) ? sd[tid - off] : 0;
    __syncthreads();
    sd[tid] += t;
  }
  __syncthreads();
  int excl = sd[tid] - tsum + b * Tn;
#pragma unroll
  for (int j = 0; j < 4; j++) {
    of[base + j] = excl;
    offs_g[b * On + base + j] = excl;
    hist_g[b * On + base + j] = hh[j];
    excl += hh[j];
  }
  __syncthreads();
#pragma unroll
  for (int i = 0; i < 4; i++) h[tid + i * 1024] = 0;   // reuse as fill
  __syncthreads();
#pragma unroll
  for (int j = 0; j < 16; j++) {
    int t = j * 1024 + tid;
    int pos = of[ov[j]] + atomicAdd(&h[ov[j]], 1);
    eidx[pos] = (unsigned short)t;
  }
}

// ---- object projection (persistent weights): objSO[r] = [obj[r]@W1s | obj[r]@W1o], bf16
// grid 512, 4 tiles of 64 rows each; W1s+W1o resident (64KB) + A 16KB -> 2 blocks/CU
__global__ __launch_bounds__(512, 2) void objproj(
    const float* __restrict__ obj, const short* __restrict__ w1t,
    unsigned short* __restrict__ objSO)
{
  __shared__ __align__(16) char lds[81920];
  const int WOF = 0, AOF = 65536;
  int tid = threadIdx.x;
  {
    int n = tid >> 2, q = tid & 3;
    int swz = (n & 7) << 4;
    const short* s1 = w1t + n * 384 + q * 32;          // W1s: k 0..127
    const short* s2 = w1t + n * 384 + 256 + q * 32;    // W1o: k 256..383
#pragma unroll
    for (int i = 0; i < 4; i++) {
      *(short8*)(lds + WOF + n * 256 + ((q * 64 + i * 16) ^ swz)) = *(const short8*)(s1 + i * 8);
      *(short8*)(lds + WOF + 32768 + n * 256 + ((q * 64 + i * 16) ^ swz)) = *(const short8*)(s2 + i * 8);
    }
  }
  int wave = tid >> 6, lane = tid & 63;
  int l15 = lane & 15, l4 = lane >> 4;
  int mg = wave >> 2, ng = wave & 3;
  int r = tid >> 3, seg = tid & 7;
  int rswz = (r & 7) << 4;

  for (int it = 0; it < 4; it++) {
    int row0 = (blockIdx.x * 4 + it) * 64;
    if (it) __syncthreads();   // previous tile's A reads done
    {
      const float* src = obj + (size_t)(row0 + r) * Dn + seg * 16;
      float4 v0 = *(const float4*)(src);
      float4 v1 = *(const float4*)(src + 4);
      float4 v2 = *(const float4*)(src + 8);
      float4 v3 = *(const float4*)(src + 12);
      short8 p0, p1;
      p0[0]=f2bf(v0.x); p0[1]=f2bf(v0.y); p0[2]=f2bf(v0.z); p0[3]=f2bf(v0.w);
      p0[4]=f2bf(v1.x); p0[5]=f2bf(v1.y); p0[6]=f2bf(v1.z); p0[7]=f2bf(v1.w);
      p1[0]=f2bf(v2.x); p1[1]=f2bf(v2.y); p1[2]=f2bf(v2.z); p1[3]=f2bf(v2.w);
      p1[4]=f2bf(v3.x); p1[5]=f2bf(v3.y); p1[6]=f2bf(v3.z); p1[7]=f2bf(v3.w);
      *(short8*)(lds + AOF + r * 256 + ((seg * 32) ^ rswz)) = p0;
      *(short8*)(lds + AOF + r * 256 + ((seg * 32 + 16) ^ rswz)) = p1;
    }
    __syncthreads();
#pragma unroll
    for (int half = 0; half < 2; half++) {
      f32x4 acc[2][2] = {};
#pragma unroll
      for (int kk = 0; kk < 4; kk++) {
        short8 a[2], bb[2];
#pragma unroll
        for (int m = 0; m < 2; m++) {
          int row = mg * 32 + m * 16 + l15;
          a[m] = *(short8*)(lds + AOF + row * 256 + ((kk * 64 + 16 * l4) ^ ((row & 7) << 4)));
        }
#pragma unroll
        for (int n = 0; n < 2; n++) {
          int nr = ng * 32 + n * 16 + l15;
          bb[n] = *(short8*)(lds + WOF + half * 32768 + nr * 256 + ((kk * 64 + 16 * l4) ^ ((nr & 7) << 4)));
        }
#pragma unroll
        for (int m = 0; m < 2; m++)
#pragma unroll
          for (int n = 0; n < 2; n++)
            acc[m][n] = __builtin_amdgcn_mfma_f32_16x16x32_bf16(a[m], bb[n], acc[m][n], 0, 0, 0);
      }
#pragma unroll
      for (int n = 0; n < 2; n++) {
        int col = ng * 32 + n * 16 + l15;
#pragma unroll
        for (int m = 0; m < 2; m++)
#pragma unroll
          for (int rr = 0; rr < 4; rr++) {
            int row = mg * 32 + m * 16 + l4 * 4 + rr;
            objSO[(size_t)(row0 + row) * 256 + half * 128 + col] =
                (unsigned short)f2bf(acc[m][n][rr]);
          }
      }
    }
  }
}

// ---- edge MLP v6: persistent weights + double-buffered A/g pipeline.
// grid 256 (1 block/CU), 512 thr, 32 M-tiles of 64 rows per block.
// LDS 144KB: w1p 32K + w2 64K resident; A dbuf 2x16K; g 16K.
#define ENT 32
__global__ __launch_bounds__(512, 2) void edge_mlp(
    const float* __restrict__ pred, const int* __restrict__ edges,
    const unsigned short* __restrict__ objSO,
    const short* __restrict__ w1t, const short* __restrict__ w2t,
    const float* __restrict__ b1, const float* __restrict__ g1, const float* __restrict__ be1,
    const float* __restrict__ b2, const float* __restrict__ g2, const float* __restrict__ be2,
    float* __restrict__ out_p, unsigned short* __restrict__ o_scr)
{
  __shared__ __align__(16) char lds[147456];
  const int W1P = 0;        // 32K: w1p (rows 0..127 x 256B, swz)
  const int W2O = 32768;    // 64K: w2  (rows 0..255 x 256B, swz)
  const int AB0 = 98304;    // 16K
  const int AB1 = 114688;   // 16K
  const int GOF = 131072;   // 16K: g = objS[s]+objO[o]

  const float invs = 1.0f / sqrtf(1.001f);
  int tid = threadIdx.x;

  // resident weight staging (once per block)
  {
    int n = tid >> 2, q = tid & 3;
    int swz = (n & 7) << 4;
    const short* src = w1t + n * 384 + 128 + q * 32;
#pragma unroll
    for (int i = 0; i < 4; i++)
      *(short8*)(lds + W1P + n * 256 + ((q * 64 + i * 16) ^ swz)) = *(const short8*)(src + i * 8);
  }
  {
    int n = tid >> 1, q = tid & 1;
    int swz = (n & 7) << 4;
    const short* src = w2t + n * 128 + q * 64;
#pragma unroll
    for (int i = 0; i < 8; i++)
      *(short8*)(lds + W2O + n * 256 + ((q * 128 + i * 16) ^ swz)) = *(const short8*)(src + i * 8);
  }

  int r = tid >> 3, seg = tid & 7;
  int rswz = (r & 7) << 4;

  float4 pv0, pv1, pv2, pv3;
  short8 sv0, sv1, ov0, ov1;

  auto load_tile = [&](int gt) {
    int b_ = gt >> 8;
    int t = ((gt & 255) << 6) + r;
    const float* src = pred + ((size_t)(b_ * Tn + t)) * Dn + seg * 16;
    pv0 = *(const float4*)(src);
    pv1 = *(const float4*)(src + 4);
    pv2 = *(const float4*)(src + 8);
    pv3 = *(const float4*)(src + 12);
    int2 e = *(const int2*)&edges[((size_t)(b_ * Tn + t)) * 2];
    const unsigned short* srow = objSO + ((size_t)(b_ * On + e.x)) * 256 + seg * 16;
    const unsigned short* orow = objSO + ((size_t)(b_ * On + e.y)) * 256 + 128 + seg * 16;
    sv0 = *(const short8*)(srow);
    sv1 = *(const short8*)(srow + 8);
    ov0 = *(const short8*)(orow);
    ov1 = *(const short8*)(orow + 8);
  };

  auto store_stage = [&](int abuf) {
    short8 p0, p1;
    p0[0]=f2bf(pv0.x); p0[1]=f2bf(pv0.y); p0[2]=f2bf(pv0.z); p0[3]=f2bf(pv0.w);
    p0[4]=f2bf(pv1.x); p0[5]=f2bf(pv1.y); p0[6]=f2bf(pv1.z); p0[7]=f2bf(pv1.w);
    p1[0]=f2bf(pv2.x); p1[1]=f2bf(pv2.y); p1[2]=f2bf(pv2.z); p1[3]=f2bf(pv2.w);
    p1[4]=f2bf(pv3.x); p1[5]=f2bf(pv3.y); p1[6]=f2bf(pv3.z); p1[7]=f2bf(pv3.w);
    *(short8*)(lds + abuf + r * 256 + ((seg * 32) ^ rswz)) = p0;
    *(short8*)(lds + abuf + r * 256 + ((seg * 32 + 16) ^ rswz)) = p1;
    short8 g0, g1v;
#pragma unroll
    for (int j = 0; j < 8; j++) {
      g0[j]  = f2bf(bf2f((unsigned short)sv0[j]) + bf2f((unsigned short)ov0[j]));
      g1v[j] = f2bf(bf2f((unsigned short)sv1[j]) + bf2f((unsigned short)ov1[j]));
    }
    *(short8*)(lds + GOF + r * 256 + ((seg * 32) ^ rswz)) = g0;
    *(short8*)(lds + GOF + r * 256 + ((seg * 32 + 16) ^ rswz)) = g1v;
  };

  int tile0 = blockIdx.x * ENT;
  load_tile(tile0);
  store_stage(AB0);
  load_tile(tile0 + 1);
  __syncthreads();

  int wave = tid >> 6, lane = tid & 63;
  int l15 = lane & 15, l4 = lane >> 4;
  int mg = wave >> 2, ng = wave & 3;
  int cur = 0;

  for (int it = 0; it < ENT; ++it) {
    int gt = tile0 + it;
    int b_ = gt >> 8, t0v = (gt & 255) << 6;
    int abuf = cur ? AB1 : AB0;
    int nbuf = cur ? AB0 : AB1;

    // ---- GEMM1: A @ w1p (64x128 @ 128x128); wave tile 32x32
    f32x4 acc1[2][2] = {};
#pragma unroll
    for (int kk = 0; kk < 4; kk++) {
      short8 a[2], bb[2];
#pragma unroll
      for (int m = 0; m < 2; m++) {
        int row = mg * 32 + m * 16 + l15;
        a[m] = *(short8*)(lds + abuf + row * 256 + ((kk * 64 + 16 * l4) ^ ((row & 7) << 4)));
      }
#pragma unroll
      for (int n = 0; n < 2; n++) {
        int nr = ng * 32 + n * 16 + l15;
        bb[n] = *(short8*)(lds + W1P + nr * 256 + ((kk * 64 + 16 * l4) ^ ((nr & 7) << 4)));
      }
#pragma unroll
      for (int m = 0; m < 2; m++)
#pragma unroll
        for (int n = 0; n < 2; n++)
          acc1[m][n] = __builtin_amdgcn_mfma_f32_16x16x32_bf16(a[m], bb[n], acc1[m][n], 0, 0, 0);
    }
    __syncthreads();   // A reads done before h1 overwrites

    // ---- epi1: h1 = relu((acc1 + g)*gs + add) -> abuf
#pragma unroll
    for (int n = 0; n < 2; n++) {
      int col = ng * 32 + n * 16 + l15;
      float gs = g1[col] * invs;
      float add = b1[col] * gs + be1[col];
#pragma unroll
      for (int m = 0; m < 2; m++)
#pragma unroll
        for (int rr = 0; rr < 4; rr++) {
          int row = mg * 32 + m * 16 + l4 * 4 + rr;
          float gv = bf2f(*(const unsigned short*)(lds + GOF + row * 256 + ((col * 2) ^ ((row & 7) << 4))));
          float v = fmaxf((acc1[m][n][rr] + gv) * gs + add, 0.0f);
          *(short*)(lds + abuf + row * 256 + ((col * 2) ^ ((row & 7) << 4))) = f2bf(v);
        }
    }
    __syncthreads();   // h1 visible; g reads done

    // ---- stage next tile into the free buffer; prefetch tile after next
    if (it + 1 < ENT) store_stage(nbuf);
    if (it + 2 < ENT) load_tile(tile0 + it + 2);

    // ---- GEMM2: h1 @ w2 (64x128 @ 128x256); wave tile 32x64
    f32x4 acc2[2][4] = {};
#pragma unroll
    for (int kk = 0; kk < 4; kk++) {
      short8 a[2], bb[4];
#pragma unroll
      for (int m = 0; m < 2; m++) {
        int row = mg * 32 + m * 16 + l15;
        a[m] = *(short8*)(lds + abuf + row * 256 + ((kk * 64 + 16 * l4) ^ ((row & 7) << 4)));
      }
#pragma unroll
      for (int n = 0; n < 4; n++) {
        int nr = ng * 64 + n * 16 + l15;
        bb[n] = *(short8*)(lds + W2O + nr * 256 + ((kk * 64 + 16 * l4) ^ ((nr & 7) << 4)));
      }
#pragma unroll
      for (int m = 0; m < 2; m++)
#pragma unroll
        for (int n = 0; n < 4; n++)
          acc2[m][n] = __builtin_amdgcn_mfma_f32_16x16x32_bf16(a[m], bb[n], acc2[m][n], 0, 0, 0);
    }
#pragma unroll
    for (int n = 0; n < 4; n++) {
      int colp = ng * 64 + n * 16 + l15;   // 0..255
      int c2 = 128 + colp;
      float gs = g2[c2] * invs;
      float add = b2[c2] * gs + be2[c2];
#pragma unroll
      for (int m = 0; m < 2; m++)
#pragma unroll
        for (int rr = 0; rr < 4; rr++) {
          int row = mg * 32 + m * 16 + l4 * 4 + rr;
          float v = fmaxf(acc2[m][n][rr] * gs + add, 0.0f);
          if (colp < 128) {
            out_p[(size_t)(b_ * Tn + t0v + row) * 128 + colp] = v;
          } else {
            o_scr[(size_t)(b_ * Tn + t0v + row) * 128 + (colp - 128)] =
                (unsigned short)f2bf(v);
          }
        }
    }
    __syncthreads();   // h1 reads + stage writes settle
    cur ^= 1;
  }
}

// ---- object MLP (pooling fused): gather-mean from o_scr, GEMM3 -> GEMM4
__global__ __launch_bounds__(256) void obj_mlp(
    const unsigned short* __restrict__ o_scr, const int* __restrict__ hist,
    const int* __restrict__ offs, const unsigned short* __restrict__ eidx,
    float* __restrict__ out_obj,
    const short* __restrict__ w3t, const short* __restrict__ w4t,
    const float* __restrict__ b3, const float* __restrict__ g3, const float* __restrict__ be3,
    const float* __restrict__ b4, const float* __restrict__ g4, const float* __restrict__ be4)
{
  __shared__ short xs[64][136];
  __shared__ short hs[64][136];
  const float invs = 1.0f / sqrtf(1.001f);
  int row0 = blockIdx.x * 64;
  int tid = threadIdx.x;

  {
    int r = tid >> 2, seg = tid & 3;
    int rg = row0 + r;
    int bb_ = rg >> 12;
    int cnt = hist[rg], start = offs[rg];
    float sum[32];
#pragma unroll
    for (int j = 0; j < 32; j++) sum[j] = 0.f;
    for (int k = 0; k < cnt; k++) {
      int t = eidx[start + k];
      const unsigned short* src = o_scr + ((size_t)(bb_ * Tn + t)) * 128 + seg * 32;
#pragma unroll
      for (int i = 0; i < 4; i++) {
        short8 v = *(const short8*)(src + i * 8);
#pragma unroll
        for (int j = 0; j < 8; j++) sum[i * 8 + j] += bf2f((unsigned short)v[j]);
      }
    }
    float ic = 1.0f / fmaxf((float)cnt, 1.0f);
#pragma unroll
    for (int i = 0; i < 4; i++) {
      short8 pk;
#pragma unroll
      for (int j = 0; j < 8; j++) pk[j] = f2bf(sum[i * 8 + j] * ic);
      *(short8*)&xs[r][seg * 32 + i * 8] = pk;
    }
  }
  __syncthreads();

  int wave = tid >> 6, lane = tid & 63;
  int l15 = lane & 15, l4 = lane >> 4;
  int n0 = wave * 32;

  f32x4 acc[4][2] = {};
  for (int kk = 0; kk < 4; kk++) {
    int k0 = kk * 32;
    short8 a[4], bb[2];
#pragma unroll
    for (int m = 0; m < 4; m++) a[m] = *(short8*)&xs[m * 16 + l15][k0 + 8 * l4];
#pragma unroll
    for (int n = 0; n < 2; n++) bb[n] = *(const short8*)&w3t[(n0 + n * 16 + l15) * 128 + k0 + 8 * l4];
#pragma unroll
    for (int m = 0; m < 4; m++)
#pragma unroll
      for (int n = 0; n < 2; n++)
        acc[m][n] = __builtin_amdgcn_mfma_f32_16x16x32_bf16(a[m], bb[n], acc[m][n], 0, 0, 0);
  }
#pragma unroll
  for (int n = 0; n < 2; n++) {
    int col = n0 + n * 16 + l15;
    float gs = g3[col] * invs;
    float add = b3[col] * gs + be3[col];
#pragma unroll
    for (int m = 0; m < 4; m++)
#pragma unroll
      for (int rr = 0; rr < 4; rr++) {
        float v = fmaxf(acc[m][n][rr] * gs + add, 0.0f);
        hs[m * 16 + l4 * 4 + rr][col] = f2bf(v);
      }
  }
  __syncthreads();

  f32x4 acc2[4][2] = {};
  for (int kk = 0; kk < 4; kk++) {
    int k0 = kk * 32;
    short8 a[4], bb[2];
#pragma unroll
    for (int m = 0; m < 4; m++) a[m] = *(short8*)&hs[m * 16 + l15][k0 + 8 * l4];
#pragma unroll
    for (int n = 0; n < 2; n++) bb[n] = *(const short8*)&w4t[(n0 + n * 16 + l15) * 128 + k0 + 8 * l4];
#pragma unroll
    for (int m = 0; m < 4; m++)
#pragma unroll
      for (int n = 0; n < 2; n++)
        acc2[m][n] = __builtin_amdgcn_mfma_f32_16x16x32_bf16(a[m], bb[n], acc2[m][n], 0, 0, 0);
  }
#pragma unroll
  for (int n = 0; n < 2; n++) {
    int col = n0 + n * 16 + l15;
    float gs = g4[col] * invs;
    float add = b4[col] * gs + be4[col];
#pragma unroll
    for (int m = 0; m < 4; m++)
#pragma unroll
      for (int rr = 0; rr < 4; rr++) {
        int row = m * 16 + l4 * 4 + rr;
        float v = fmaxf(acc2[m][n][rr] * gs + add, 0.0f);
        out_obj[(size_t)(row0 + row) * 128 + col] = v;
      }
  }
}

extern "C" void kernel_launch(void* const* d_in, const int* in_sizes, int n_in,
                              void* d_out, int out_size, void* d_ws, size_t ws_size,
                              hipStream_t stream) {
  const float* obj  = (const float*)d_in[0];
  const float* pred = (const float*)d_in[1];
  const int*   edges= (const int*)d_in[2];
  const float* W1 = (const float*)d_in[3];
  const float* b1 = (const float*)d_in[4];
  const float* g1 = (const float*)d_in[5];
  const float* be1= (const float*)d_in[6];
  const float* W2 = (const float*)d_in[7];
  const float* b2 = (const float*)d_in[8];
  const float* g2 = (const float*)d_in[9];
  const float* be2= (const float*)d_in[10];
  const float* W3 = (const float*)d_in[11];
  const float* b3 = (const float*)d_in[12];
  const float* g3 = (const float*)d_in[13];
  const float* be3= (const float*)d_in[14];
  const float* W4 = (const float*)d_in[15];
  const float* b4 = (const float*)d_in[16];
  const float* g4 = (const float*)d_in[17];
  const float* be4= (const float*)d_in[18];

  float* out_obj = (float*)d_out;                           // B*O*128
  float* out_p   = (float*)d_out + (size_t)Bn * On * 128;   // B*T*128
  // objSO (bf16 B*O*256 = 67 MB) lives in the out_obj region (dead until obj_mlp)
  unsigned short* objSO = (unsigned short*)d_out;

  char* ws = (char*)d_ws;
  short* w1t = (short*)(ws);
  short* w2t = (short*)(ws + 49152 * 2);
  short* w3t = (short*)(ws + (49152 + 32768) * 2);
  short* w4t = (short*)(ws + (49152 + 32768 + 16384) * 2);

  const size_t OFF_HIST = 262144;
  const size_t OFF_OFFS = OFF_HIST + 524288;
  const size_t OFF_EIDX = OFF_OFFS + 1048576;     // u16 B*T = 1 MB
  const size_t OFF_OSCR = 4194304;                // bf16 B*T*128 = 128 MiB

  int* hist = (int*)(ws + OFF_HIST);
  int* offs = (int*)(ws + OFF_OFFS);
  unsigned short* eidx = (unsigned short*)(ws + OFF_EIDX);
  unsigned short* o_scr = (unsigned short*)(ws + OFF_OSCR);

  prep_weights<<<448, 256, 0, stream>>>(W1, W2, W3, W4, w1t, w2t, w3t, w4t);
  sort_kernel<<<Bn, 1024, 0, stream>>>(edges, hist, offs, eidx);
  objproj<<<512, 512, 0, stream>>>(obj, w1t, objSO);
  edge_mlp<<<256, 512, 0, stream>>>(pred, edges, objSO, w1t, w2t,
      b1, g1, be1, b2, g2, be2, out_p, o_scr);
  obj_mlp<<<(Bn * On) / 64, 256, 0, stream>>>(o_scr, hist, offs, eidx, out_obj,
      w3t, w4t, b3, g3, be3, b4, g4, be4);
}